// Round 19
// baseline (99.920 us; speedup 1.0000x reference)
//
#include <hip/hip_runtime.h>
#include <math.h>

#define BATCH  2048
#define FEAT   2048
#define LUTSZ  64
#define TF     256
#define GROUPS 64
#define RPB    32            // rows per block
#define ITERS  (RPB / 2)     // 2 rows per iteration

typedef float f32x2 __attribute__((ext_vector_type(2)));
typedef int   i32x2 __attribute__((ext_vector_type(2)));
typedef float f32x4 __attribute__((ext_vector_type(4)));

// ---------------------------------------------------------------------------
// Round-19 = round-18 (99.6us) + depth-2 r prefetch.
//
// Little's law: per CU, in-flight r was 16 waves x 1536B ~= 24.6KB -- exactly
// the edge for ~27 GB/s/CU at loaded-HBM latency. Holding r(i),r(i+1) in
// registers and issuing r(i+2) each iteration doubles in-flight r bytes.
// (r15's depth-2-r test was confounded by the regressed TF=128 config.)
//
// Carried (all proven): TF=256 tile + 2-slot block-shared x (r14), XCD
// group-pin swizzle fid=tile*64+grp (r16, -17%), ballot transpose (r9),
// lgkmcnt-only barriers keeping vmem in flight (r14), unconditional slut
// precompute with d_out as L1 intermediate (r17), setprio critical section
// + depth-2 x prefetch (r18), exact f32 chain:
// (v+1.0f)*0.5f ; sigmoid = 1.0f/(1.0f + RN32(exp_f64(-v))).
// ---------------------------------------------------------------------------

__device__ __forceinline__ void barrier_keep_vm() {
    __builtin_amdgcn_sched_barrier(0);
    asm volatile("s_waitcnt lgkmcnt(0)\n\ts_barrier" ::: "memory");
    __builtin_amdgcn_sched_barrier(0);
}

__global__ __launch_bounds__(256) void sigmoid_lut_kernel(
    const float* __restrict__ lut1, const float* __restrict__ lut2,
    float* __restrict__ slut1, float* __restrict__ slut2)
{
    const int n = FEAT * LUTSZ;
    int i = blockIdx.x * 256 + threadIdx.x;
    if (i < n) {
        float v = lut1[i];
        float e = (float)exp(-(double)v);     // correctly-rounded f32 exp
        slut1[i] = 1.0f / (1.0f + e);         // f32 IEEE chain (matches np)
    } else {
        i -= n;
        float v = lut2[i];
        float e = (float)exp(-(double)v);
        slut2[i] = 1.0f / (1.0f + e);
    }
}

// L: 0 = transform-in, 1 = plain input (lutg is slut or raw lut3)
template<int L>
__global__ __launch_bounds__(512, 4) void lut_tile2(
    const float* __restrict__ xin, const float* __restrict__ rr,
    const int* __restrict__ connect, const float* __restrict__ lutg,
    float* __restrict__ yout)
{
    __shared__ float sl[TF * LUTSZ];   // 64 KiB
    __shared__ float xsh[2][FEAT];     // 16 KiB  (2 row slots)

    // XCD swizzle: fid = tile*GROUPS + grp -> the 8 tile-blocks of a group
    // share fid mod 8 -> same XCD -> shared x rows are local-L2 hits.
    const int fid  = blockIdx.x;
    const int tile = fid >> 6;          // 0..7
    const int grp  = fid & 63;          // 0..63
    const int f0   = tile * TF;
    const int tid  = threadIdx.x, lane = tid & 63, w = tid >> 6;
    const int slot = w >> 2;           // 0/1: which row this wave computes
    const int ch   = w & 3;            // which 64-feature chunk
    const int fc   = f0 + ch * 64;

    // ---- stage lut tile (already sigmoid'd for layers 1-2) ----
    for (int i = tid; i < TF * LUTSZ; i += 512)
        sl[i] = lutg[(size_t)f0 * LUTSZ + i];

    // ---- connect regs for this wave's chunk (scrambled ballot layout) ----
    i32x2 cc0, cc1, cc2;
    {
        const i32x2* cg = reinterpret_cast<const i32x2*>(
            connect + (size_t)fc * 6);
        cc0 = cg[lane]; cc1 = cg[64 + lane]; cc2 = cg[128 + lane];
    }

    const int b0 = grp * RPB;

    // x staging map: thread covers 4 floats at xcol and 4 at xcol+1024 of
    // row (b0 + 2i + xrow_off)  -> conflict-free b128 LDS writes.
    const int xrow_off = tid >> 8;          // 0/1
    const int xcol     = (tid & 255) * 4;   // float offset

    // ---- prologue: stage x(0); issue x(1); load r(0); issue r(1) ----
    f32x4 pxa, pxb;                     // x for the NEXT write
    {
        const float* xp = xin + (size_t)(b0 + xrow_off) * FEAT;
        f32x4 a = *reinterpret_cast<const f32x4*>(xp + xcol);
        f32x4 b = *reinterpret_cast<const f32x4*>(xp + xcol + 1024);
        if (L == 0) { a = (a + 1.0f) * 0.5f; b = (b + 1.0f) * 0.5f; }
        *reinterpret_cast<f32x4*>(&xsh[xrow_off][xcol])        = a;
        *reinterpret_cast<f32x4*>(&xsh[xrow_off][xcol + 1024]) = b;
    }
    {
        const float* xp = xin + (size_t)(b0 + 2 + xrow_off) * FEAT;
        pxa = *reinterpret_cast<const f32x4*>(xp + xcol);
        pxb = *reinterpret_cast<const f32x4*>(xp + xcol + 1024);
    }
    f32x2 r0, r1, r2;                   // r(i)   -- current
    f32x2 p0, p1, p2;                   // r(i+1) -- in flight / arrived
    {
        const f32x2* rg = reinterpret_cast<const f32x2*>(
            rr + ((size_t)(b0 + slot) * FEAT + fc) * 6);
        r0 = rg[lane]; r1 = rg[64 + lane]; r2 = rg[128 + lane];
    }
    {
        const f32x2* rg = reinterpret_cast<const f32x2*>(
            rr + ((size_t)(b0 + 2 + slot) * FEAT + fc) * 6);
        p0 = rg[lane]; p1 = rg[64 + lane]; p2 = rg[128 + lane];
    }
    barrier_keep_vm();   // sl + xsh visible to all waves

    for (int i = 0; i < ITERS; ++i) {
        const int b = b0 + 2 * i + slot;

        // ---- issue depth-2 prefetches: x(i+2), r(i+2) ----
        f32x4 qxa, qxb;
        if (i + 2 < ITERS) {
            const float* xp = xin + (size_t)(b0 + 2 * (i + 2) + xrow_off) * FEAT;
            qxa = *reinterpret_cast<const f32x4*>(xp + xcol);
            qxb = *reinterpret_cast<const f32x4*>(xp + xcol + 1024);
        }
        f32x2 q0, q1, q2;
        if (i + 2 < ITERS) {
            const f32x2* rg = reinterpret_cast<const f32x2*>(
                rr + ((size_t)(b + 4) * FEAT + fc) * 6);
            q0 = rg[lane]; q1 = rg[64 + lane]; q2 = rg[128 + lane];
        }

        // ---- critical section: ballot transpose + LDS lut gather ----
        __builtin_amdgcn_s_setprio(1);
        const float* xw = xsh[slot];
        const unsigned long long B0 = __ballot(xw[cc0[0]] >= r0[0]);
        const unsigned long long B1 = __ballot(xw[cc0[1]] >= r0[1]);
        const unsigned long long B2 = __ballot(xw[cc1[0]] >= r1[0]);
        const unsigned long long B3 = __ballot(xw[cc1[1]] >= r1[1]);
        const unsigned long long B4 = __ballot(xw[cc2[0]] >= r2[0]);
        const unsigned long long B5 = __ballot(xw[cc2[1]] >= r2[1]);

        int idx = 0;
        #pragma unroll
        for (int j = 0; j < 6; ++j) {
            const int e = 6 * lane + j;          // even => e&1 == j&1
            const int g = e >> 7;
            const unsigned long long src =
                (j & 1) ? ((g == 0) ? B1 : (g == 1) ? B3 : B5)
                        : ((g == 0) ? B0 : (g == 1) ? B2 : B4);
            idx |= (int)((src >> ((e & 127) >> 1)) & 1ull) << j;
        }

        const float v = sl[(ch * 64 + lane) * LUTSZ + idx];
        yout[(size_t)b * FEAT + fc + lane] = v;
        __builtin_amdgcn_s_setprio(0);

        // ---- rotate r registers (depth-2) ----
        r0 = p0; r1 = p1; r2 = p2;
        p0 = q0; p1 = q1; p2 = q2;

        // ---- rotate the shared x buffer (write 2-phase-old loads) ----
        barrier_keep_vm();                // all waves done gathering iter i
        if (i + 1 < ITERS) {
            f32x4 a = pxa, bb = pxb;      // issued at iter i-1: vmcnt wait ~0
            if (L == 0) { a = (a + 1.0f) * 0.5f; bb = (bb + 1.0f) * 0.5f; }
            *reinterpret_cast<f32x4*>(&xsh[xrow_off][xcol])        = a;
            *reinterpret_cast<f32x4*>(&xsh[xrow_off][xcol + 1024]) = bb;
            barrier_keep_vm();            // new rows visible
        }
        pxa = qxa; pxb = qxb;
    }
}

extern "C" void kernel_launch(void* const* d_in, const int* in_sizes, int n_in,
                              void* d_out, int out_size, void* d_ws, size_t ws_size,
                              hipStream_t stream) {
    const float* inputs = (const float*)d_in[0];
    const float* r1     = (const float*)d_in[1];
    const float* r2     = (const float*)d_in[2];
    const float* r3     = (const float*)d_in[3];
    const float* lut1   = (const float*)d_in[4];
    const float* lut2   = (const float*)d_in[5];
    const float* lut3   = (const float*)d_in[6];
    const int*   c1     = (const int*)d_in[7];
    const int*   c2     = (const int*)d_in[8];
    const int*   c3     = (const int*)d_in[9];
    float* out = (float*)d_out;

    const size_t lutn = (size_t)FEAT * LUTSZ;

    // ws layout: slut1 | slut2 | ws2   (17.8 MB total -- always fits)
    float* slut1 = (float*)d_ws;
    float* slut2 = slut1 + lutn;
    float* ws2   = slut2 + lutn;
    float* ws1   = out;                 // d_out doubles as L1 intermediate

    dim3 grid((FEAT / TF) * GROUPS), block(512);   // flat 512 blocks, swizzled

    sigmoid_lut_kernel<<<dim3(2 * lutn / 256), dim3(256), 0, stream>>>(
        lut1, lut2, slut1, slut2);

    lut_tile2<0><<<grid, block, 0, stream>>>(inputs, r1, c1, slut1, ws1);
    lut_tile2<1><<<grid, block, 0, stream>>>(ws1,    r2, c2, slut2, ws2);
    lut_tile2<1><<<grid, block, 0, stream>>>(ws2,    r3, c3, lut3,  out);
}

// Round 20
// 98.082 us; speedup vs baseline: 1.0187x; 1.0187x over previous
//
#include <hip/hip_runtime.h>
#include <math.h>

#define BATCH  2048
#define FEAT   2048
#define LUTSZ  64
#define TF     256
#define GROUPS 64
#define RPB    32            // rows per block
#define ITERS  (RPB / 2)     // 2 rows per iteration

typedef float f32x2 __attribute__((ext_vector_type(2)));
typedef int   i32x2 __attribute__((ext_vector_type(2)));
typedef float f32x4 __attribute__((ext_vector_type(4)));

// ---------------------------------------------------------------------------
// Round-20 = round-18 (99.6us; depth-2 r reverted -- r19 proved it null) +
// staging-burst fixes:
//  * lut tile staged with f32x4 (8 x 16B/thread vs 32 scalar dwords) --
//    the one load loop that was never vectorized (Common-mistake #2).
//  * prologue vmem issues (x(0), x(1), r(0), connect) hoisted ABOVE the
//    staging loop so the r/x HBM stream flows UNDER the lut staging instead
//    of starting after it (~3-5us dead time per layer removed).
//
// Carried (all proven): TF=256 tile + 2-slot block-shared x (r14), XCD
// group-pin swizzle fid=tile*64+grp (r16, -17%), ballot transpose (r9),
// lgkmcnt-only barriers keeping vmem in flight (r14), unconditional slut
// precompute with d_out as L1 intermediate (r17), setprio critical section
// + depth-2 x prefetch (r18), exact f32 chain:
// (v+1.0f)*0.5f ; sigmoid = 1.0f/(1.0f + RN32(exp_f64(-v))).
// ---------------------------------------------------------------------------

__device__ __forceinline__ void barrier_keep_vm() {
    __builtin_amdgcn_sched_barrier(0);
    asm volatile("s_waitcnt lgkmcnt(0)\n\ts_barrier" ::: "memory");
    __builtin_amdgcn_sched_barrier(0);
}

__global__ __launch_bounds__(256) void sigmoid_lut_kernel(
    const float* __restrict__ lut1, const float* __restrict__ lut2,
    float* __restrict__ slut1, float* __restrict__ slut2)
{
    const int n = FEAT * LUTSZ;
    int i = blockIdx.x * 256 + threadIdx.x;
    if (i < n) {
        float v = lut1[i];
        float e = (float)exp(-(double)v);     // correctly-rounded f32 exp
        slut1[i] = 1.0f / (1.0f + e);         // f32 IEEE chain (matches np)
    } else {
        i -= n;
        float v = lut2[i];
        float e = (float)exp(-(double)v);
        slut2[i] = 1.0f / (1.0f + e);
    }
}

// L: 0 = transform-in, 1 = plain input (lutg is slut or raw lut3)
template<int L>
__global__ __launch_bounds__(512, 4) void lut_tile2(
    const float* __restrict__ xin, const float* __restrict__ rr,
    const int* __restrict__ connect, const float* __restrict__ lutg,
    float* __restrict__ yout)
{
    __shared__ float sl[TF * LUTSZ];   // 64 KiB
    __shared__ float xsh[2][FEAT];     // 16 KiB  (2 row slots)

    // XCD swizzle: fid = tile*GROUPS + grp -> the 8 tile-blocks of a group
    // share fid mod 8 -> same XCD -> shared x rows are local-L2 hits.
    const int fid  = blockIdx.x;
    const int tile = fid >> 6;          // 0..7
    const int grp  = fid & 63;          // 0..63
    const int f0   = tile * TF;
    const int tid  = threadIdx.x, lane = tid & 63, w = tid >> 6;
    const int slot = w >> 2;           // 0/1: which row this wave computes
    const int ch   = w & 3;            // which 64-feature chunk
    const int fc   = f0 + ch * 64;

    const int b0 = grp * RPB;

    // x staging map: thread covers 4 floats at xcol and 4 at xcol+1024 of
    // row (b0 + 2i + xrow_off)  -> conflict-free b128 LDS writes.
    const int xrow_off = tid >> 8;          // 0/1
    const int xcol     = (tid & 255) * 4;   // float offset

    // ---- issue ALL prologue vmem first: x(0), x(1), r(0), connect ----
    f32x4 x0a, x0b, pxa, pxb;
    {
        const float* xp = xin + (size_t)(b0 + xrow_off) * FEAT;
        x0a = *reinterpret_cast<const f32x4*>(xp + xcol);
        x0b = *reinterpret_cast<const f32x4*>(xp + xcol + 1024);
    }
    {
        const float* xp = xin + (size_t)(b0 + 2 + xrow_off) * FEAT;
        pxa = *reinterpret_cast<const f32x4*>(xp + xcol);
        pxb = *reinterpret_cast<const f32x4*>(xp + xcol + 1024);
    }
    f32x2 r0, r1, r2;
    {
        const f32x2* rg = reinterpret_cast<const f32x2*>(
            rr + ((size_t)(b0 + slot) * FEAT + fc) * 6);
        r0 = rg[lane]; r1 = rg[64 + lane]; r2 = rg[128 + lane];
    }
    i32x2 cc0, cc1, cc2;
    {
        const i32x2* cg = reinterpret_cast<const i32x2*>(
            connect + (size_t)fc * 6);
        cc0 = cg[lane]; cc1 = cg[64 + lane]; cc2 = cg[128 + lane];
    }

    // ---- stage lut tile, vectorized (8 x f32x4 per thread, coalesced) ----
    {
        const f32x4* lg4 = reinterpret_cast<const f32x4*>(
            lutg + (size_t)f0 * LUTSZ);
        f32x4* sl4 = reinterpret_cast<f32x4*>(sl);
        #pragma unroll
        for (int k = 0; k < 8; ++k)
            sl4[k * 512 + tid] = lg4[k * 512 + tid];
    }

    // ---- stage x(0) (loads long since in flight) ----
    {
        f32x4 a = x0a, b = x0b;
        if (L == 0) { a = (a + 1.0f) * 0.5f; b = (b + 1.0f) * 0.5f; }
        *reinterpret_cast<f32x4*>(&xsh[xrow_off][xcol])        = a;
        *reinterpret_cast<f32x4*>(&xsh[xrow_off][xcol + 1024]) = b;
    }
    barrier_keep_vm();   // sl + xsh visible to all waves

    for (int i = 0; i < ITERS; ++i) {
        const int b = b0 + 2 * i + slot;

        // ---- issue prefetches: x(i+2) [depth-2], r(i+1) ----
        f32x4 qxa, qxb;
        if (i + 2 < ITERS) {
            const float* xp = xin + (size_t)(b0 + 2 * (i + 2) + xrow_off) * FEAT;
            qxa = *reinterpret_cast<const f32x4*>(xp + xcol);
            qxb = *reinterpret_cast<const f32x4*>(xp + xcol + 1024);
        }
        f32x2 n0, n1, n2;
        if (i + 1 < ITERS) {
            const f32x2* rg = reinterpret_cast<const f32x2*>(
                rr + ((size_t)(b + 2) * FEAT + fc) * 6);
            n0 = rg[lane]; n1 = rg[64 + lane]; n2 = rg[128 + lane];
        }

        // ---- critical section: ballot transpose + LDS lut gather ----
        __builtin_amdgcn_s_setprio(1);
        const float* xw = xsh[slot];
        const unsigned long long B0 = __ballot(xw[cc0[0]] >= r0[0]);
        const unsigned long long B1 = __ballot(xw[cc0[1]] >= r0[1]);
        const unsigned long long B2 = __ballot(xw[cc1[0]] >= r1[0]);
        const unsigned long long B3 = __ballot(xw[cc1[1]] >= r1[1]);
        const unsigned long long B4 = __ballot(xw[cc2[0]] >= r2[0]);
        const unsigned long long B5 = __ballot(xw[cc2[1]] >= r2[1]);

        int idx = 0;
        #pragma unroll
        for (int j = 0; j < 6; ++j) {
            const int e = 6 * lane + j;          // even => e&1 == j&1
            const int g = e >> 7;
            const unsigned long long src =
                (j & 1) ? ((g == 0) ? B1 : (g == 1) ? B3 : B5)
                        : ((g == 0) ? B0 : (g == 1) ? B2 : B4);
            idx |= (int)((src >> ((e & 127) >> 1)) & 1ull) << j;
        }

        const float v = sl[(ch * 64 + lane) * LUTSZ + idx];
        yout[(size_t)b * FEAT + fc + lane] = v;
        __builtin_amdgcn_s_setprio(0);

        r0 = n0; r1 = n1; r2 = n2;

        // ---- rotate the shared x buffer (write 2-phase-old loads) ----
        barrier_keep_vm();                // all waves done gathering iter i
        if (i + 1 < ITERS) {
            f32x4 a = pxa, bb = pxb;      // issued at iter i-1: vmcnt wait ~0
            if (L == 0) { a = (a + 1.0f) * 0.5f; bb = (bb + 1.0f) * 0.5f; }
            *reinterpret_cast<f32x4*>(&xsh[xrow_off][xcol])        = a;
            *reinterpret_cast<f32x4*>(&xsh[xrow_off][xcol + 1024]) = bb;
            barrier_keep_vm();            // new rows visible
        }
        pxa = qxa; pxb = qxb;
    }
}

extern "C" void kernel_launch(void* const* d_in, const int* in_sizes, int n_in,
                              void* d_out, int out_size, void* d_ws, size_t ws_size,
                              hipStream_t stream) {
    const float* inputs = (const float*)d_in[0];
    const float* r1     = (const float*)d_in[1];
    const float* r2     = (const float*)d_in[2];
    const float* r3     = (const float*)d_in[3];
    const float* lut1   = (const float*)d_in[4];
    const float* lut2   = (const float*)d_in[5];
    const float* lut3   = (const float*)d_in[6];
    const int*   c1     = (const int*)d_in[7];
    const int*   c2     = (const int*)d_in[8];
    const int*   c3     = (const int*)d_in[9];
    float* out = (float*)d_out;

    const size_t lutn = (size_t)FEAT * LUTSZ;

    // ws layout: slut1 | slut2 | ws2   (17.8 MB total -- always fits)
    float* slut1 = (float*)d_ws;
    float* slut2 = slut1 + lutn;
    float* ws2   = slut2 + lutn;
    float* ws1   = out;                 // d_out doubles as L1 intermediate

    dim3 grid((FEAT / TF) * GROUPS), block(512);   // flat 512 blocks, swizzled

    sigmoid_lut_kernel<<<dim3(2 * lutn / 256), dim3(256), 0, stream>>>(
        lut1, lut2, slut1, slut2);

    lut_tile2<0><<<grid, block, 0, stream>>>(inputs, r1, c1, slut1, ws1);
    lut_tile2<1><<<grid, block, 0, stream>>>(ws1,    r2, c2, slut2, ws2);
    lut_tile2<1><<<grid, block, 0, stream>>>(ws2,    r3, c3, lut3,  out);
}